// Round 1
// baseline (436.346 us; speedup 1.0000x reference)
//
#include <hip/hip_runtime.h>

// 3-level 2D Haar DWT, x: (16, 64, 256, 256) fp32.
// No padding occurs (all dims even, pad=(0,0)). Stride-2 filt-2 => non-overlapping
// 2x2 blocks, zero halo: fully fused, register-only, no LDS.
//
// Output concat order (pytree leaves): l3, lh3, hl3, hh3, lh2, hl2, hh2, lh1, hl1, hh1

#define PLANES   1024          // 16*64
#define S3       1048576       // 1024*32*32
#define S2       4194304       // 1024*64*64
#define S1       16777216      // 1024*128*128

__global__ __launch_bounds__(256) void dwt3_haar(const float* __restrict__ x,
                                                 float* __restrict__ out) {
    const int bid = blockIdx.x;
    const int p   = bid >> 2;     // plane index (b*64+c)
    const int s   = bid & 3;      // 64-row strip within plane
    const int tid = threadIdx.x;
    const int tx  = tid & 31;     // 0..31 -> 8-col block
    const int ty  = tid >> 5;     // 0..7  -> 8-row block within strip

    const float* in = x + (size_t)p * 65536
                        + (size_t)(64 * s + 8 * ty) * 256
                        + (size_t)(8 * tx);

    float* __restrict__ l3  = out;
    float* __restrict__ lh3 = out + (size_t)S3;
    float* __restrict__ hl3 = out + (size_t)2 * S3;
    float* __restrict__ hh3 = out + (size_t)3 * S3;
    float* __restrict__ lh2 = out + (size_t)4 * S3;
    float* __restrict__ hl2 = out + (size_t)4 * S3 + S2;
    float* __restrict__ hh2 = out + (size_t)4 * S3 + 2 * (size_t)S2;
    float* __restrict__ lh1 = out + (size_t)4 * S3 + 3 * (size_t)S2;
    float* __restrict__ hl1 = out + (size_t)4 * S3 + 3 * (size_t)S2 + (size_t)S1;
    float* __restrict__ hh1 = out + (size_t)4 * S3 + 3 * (size_t)S2 + 2 * (size_t)S1;

    float ll1[4][4];

    // ---- Level 1: 8x8 input block -> 4x4 per subband (128x128 planes) ----
#pragma unroll
    for (int rp = 0; rp < 4; ++rp) {
        const float4 r0a = *(const float4*)(in + (size_t)(2 * rp) * 256);
        const float4 r0b = *(const float4*)(in + (size_t)(2 * rp) * 256 + 4);
        const float4 r1a = *(const float4*)(in + (size_t)(2 * rp + 1) * 256);
        const float4 r1b = *(const float4*)(in + (size_t)(2 * rp + 1) * 256 + 4);
        const float r0[8] = {r0a.x, r0a.y, r0a.z, r0a.w, r0b.x, r0b.y, r0b.z, r0b.w};
        const float r1[8] = {r1a.x, r1a.y, r1a.z, r1a.w, r1b.x, r1b.y, r1b.z, r1b.w};

        float lhv[4], hlv[4], hhv[4];
#pragma unroll
        for (int j = 0; j < 4; ++j) {
            const float a = r0[2 * j], b = r0[2 * j + 1];
            const float c = r1[2 * j], d = r1[2 * j + 1];
            const float s1 = a + b, s2 = c + d;
            const float d1 = a - b, d2 = c - d;
            ll1[rp][j] = 0.5f * (s1 + s2);
            lhv[j]     = 0.5f * (s1 - s2);
            hlv[j]     = 0.5f * (d1 + d2);
            hhv[j]     = 0.5f * (d1 - d2);
        }
        const size_t o1 = (size_t)p * 16384
                        + (size_t)(32 * s + 4 * ty + rp) * 128
                        + (size_t)(4 * tx);
        *(float4*)(lh1 + o1) = make_float4(lhv[0], lhv[1], lhv[2], lhv[3]);
        *(float4*)(hl1 + o1) = make_float4(hlv[0], hlv[1], hlv[2], hlv[3]);
        *(float4*)(hh1 + o1) = make_float4(hhv[0], hhv[1], hhv[2], hhv[3]);
    }

    // ---- Level 2: 4x4 LL1 -> 2x2 per subband (64x64 planes) ----
    float ll2[2][2];
#pragma unroll
    for (int rp = 0; rp < 2; ++rp) {
        float lhv[2], hlv[2], hhv[2];
#pragma unroll
        for (int j = 0; j < 2; ++j) {
            const float a = ll1[2 * rp][2 * j],     b = ll1[2 * rp][2 * j + 1];
            const float c = ll1[2 * rp + 1][2 * j], d = ll1[2 * rp + 1][2 * j + 1];
            const float s1 = a + b, s2 = c + d;
            const float d1 = a - b, d2 = c - d;
            ll2[rp][j] = 0.5f * (s1 + s2);
            lhv[j]     = 0.5f * (s1 - s2);
            hlv[j]     = 0.5f * (d1 + d2);
            hhv[j]     = 0.5f * (d1 - d2);
        }
        const size_t o2 = (size_t)p * 4096
                        + (size_t)(16 * s + 2 * ty + rp) * 64
                        + (size_t)(2 * tx);
        *(float2*)(lh2 + o2) = make_float2(lhv[0], lhv[1]);
        *(float2*)(hl2 + o2) = make_float2(hlv[0], hlv[1]);
        *(float2*)(hh2 + o2) = make_float2(hhv[0], hhv[1]);
    }

    // ---- Level 3: 2x2 LL2 -> 1x1 per subband (32x32 planes) ----
    {
        const float a = ll2[0][0], b = ll2[0][1];
        const float c = ll2[1][0], d = ll2[1][1];
        const float s1 = a + b, s2 = c + d;
        const float d1 = a - b, d2 = c - d;
        const size_t o3 = (size_t)p * 1024
                        + (size_t)(8 * s + ty) * 32
                        + (size_t)tx;
        l3[o3]  = 0.5f * (s1 + s2);
        lh3[o3] = 0.5f * (s1 - s2);
        hl3[o3] = 0.5f * (d1 + d2);
        hh3[o3] = 0.5f * (d1 - d2);
    }
}

extern "C" void kernel_launch(void* const* d_in, const int* in_sizes, int n_in,
                              void* d_out, int out_size, void* d_ws, size_t ws_size,
                              hipStream_t stream) {
    const float* x = (const float*)d_in[0];
    float* out = (float*)d_out;
    // 1024 planes * 4 strips = 4096 blocks, 256 threads each
    dwt3_haar<<<4096, 256, 0, stream>>>(x, out);
}

// Round 3
// 432.824 us; speedup vs baseline: 1.0081x; 1.0081x over previous
//
#include <hip/hip_runtime.h>

// 3-level 2D Haar DWT, x: (16, 64, 256, 256) fp32.
// No padding occurs (all dims even). Stride-2 filt-2 => non-overlapping 2x2
// blocks, zero halo: fully fused, register-only, no LDS.
//
// R3: same as R2 but nontemporal builtins use clang ext_vector_type (HIP
//     float4 is a struct and is rejected by __builtin_nontemporal_*).
//
// Output concat order: l3, lh3, hl3, hh3, lh2, hl2, hh2, lh1, hl1, hh1

#define S3       1048576       // 1024*32*32
#define S2       4194304       // 1024*64*64
#define S1       16777216      // 1024*128*128

typedef float v4f __attribute__((ext_vector_type(4)));
typedef float v2f __attribute__((ext_vector_type(2)));

__device__ __forceinline__ v4f ntload4(const float* p) {
    return __builtin_nontemporal_load((const v4f*)p);
}
__device__ __forceinline__ void ntstore4(float* p, v4f v) {
    __builtin_nontemporal_store(v, (v4f*)p);
}
__device__ __forceinline__ void ntstore2(float* p, v2f v) {
    __builtin_nontemporal_store(v, (v2f*)p);
}
__device__ __forceinline__ void ntstore1(float* p, float v) {
    __builtin_nontemporal_store(v, p);
}

__global__ __launch_bounds__(256) void dwt3_haar(const float* __restrict__ x,
                                                 float* __restrict__ out) {
    const int bid = blockIdx.x;
    const int p   = bid >> 2;     // plane index (b*64+c)
    const int s   = bid & 3;      // 64-row strip within plane
    const int tid = threadIdx.x;
    const int tx  = tid & 31;     // 0..31 -> 8-col block
    const int ty  = tid >> 5;     // 0..7  -> 8-row block within strip

    const float* in = x + (size_t)p * 65536
                        + (size_t)(64 * s + 8 * ty) * 256
                        + (size_t)(8 * tx);

    float* __restrict__ l3  = out;
    float* __restrict__ lh3 = out + (size_t)S3;
    float* __restrict__ hl3 = out + (size_t)2 * S3;
    float* __restrict__ hh3 = out + (size_t)3 * S3;
    float* __restrict__ lh2 = out + (size_t)4 * S3;
    float* __restrict__ hl2 = out + (size_t)4 * S3 + S2;
    float* __restrict__ hh2 = out + (size_t)4 * S3 + 2 * (size_t)S2;
    float* __restrict__ lh1 = out + (size_t)4 * S3 + 3 * (size_t)S2;
    float* __restrict__ hl1 = out + (size_t)4 * S3 + 3 * (size_t)S2 + (size_t)S1;
    float* __restrict__ hh1 = out + (size_t)4 * S3 + 3 * (size_t)S2 + 2 * (size_t)S1;

    // ---- Issue ALL global loads up front: 16 outstanding dwordx4 / thread ----
    v4f ra[8], rb[8];
#pragma unroll
    for (int i = 0; i < 8; ++i) {
        ra[i] = ntload4(in + (size_t)i * 256);
        rb[i] = ntload4(in + (size_t)i * 256 + 4);
    }

    float ll1[4][4];

    // ---- Level 1: 8x8 -> 4x4 per subband (128x128 planes) ----
#pragma unroll
    for (int rp = 0; rp < 4; ++rp) {
        const float r0[8] = {ra[2*rp].x, ra[2*rp].y, ra[2*rp].z, ra[2*rp].w,
                             rb[2*rp].x, rb[2*rp].y, rb[2*rp].z, rb[2*rp].w};
        const float r1[8] = {ra[2*rp+1].x, ra[2*rp+1].y, ra[2*rp+1].z, ra[2*rp+1].w,
                             rb[2*rp+1].x, rb[2*rp+1].y, rb[2*rp+1].z, rb[2*rp+1].w};

        float lhv[4], hlv[4], hhv[4];
#pragma unroll
        for (int j = 0; j < 4; ++j) {
            const float a = r0[2 * j], b = r0[2 * j + 1];
            const float c = r1[2 * j], d = r1[2 * j + 1];
            const float s1 = a + b, s2 = c + d;
            const float d1 = a - b, d2 = c - d;
            ll1[rp][j] = 0.5f * (s1 + s2);
            lhv[j]     = 0.5f * (s1 - s2);
            hlv[j]     = 0.5f * (d1 + d2);
            hhv[j]     = 0.5f * (d1 - d2);
        }
        const size_t o1 = (size_t)p * 16384
                        + (size_t)(32 * s + 4 * ty + rp) * 128
                        + (size_t)(4 * tx);
        ntstore4(lh1 + o1, (v4f){lhv[0], lhv[1], lhv[2], lhv[3]});
        ntstore4(hl1 + o1, (v4f){hlv[0], hlv[1], hlv[2], hlv[3]});
        ntstore4(hh1 + o1, (v4f){hhv[0], hhv[1], hhv[2], hhv[3]});
    }

    // ---- Level 2: 4x4 LL1 -> 2x2 per subband (64x64 planes) ----
    float ll2[2][2];
#pragma unroll
    for (int rp = 0; rp < 2; ++rp) {
        float lhv[2], hlv[2], hhv[2];
#pragma unroll
        for (int j = 0; j < 2; ++j) {
            const float a = ll1[2 * rp][2 * j],     b = ll1[2 * rp][2 * j + 1];
            const float c = ll1[2 * rp + 1][2 * j], d = ll1[2 * rp + 1][2 * j + 1];
            const float s1 = a + b, s2 = c + d;
            const float d1 = a - b, d2 = c - d;
            ll2[rp][j] = 0.5f * (s1 + s2);
            lhv[j]     = 0.5f * (s1 - s2);
            hlv[j]     = 0.5f * (d1 + d2);
            hhv[j]     = 0.5f * (d1 - d2);
        }
        const size_t o2 = (size_t)p * 4096
                        + (size_t)(16 * s + 2 * ty + rp) * 64
                        + (size_t)(2 * tx);
        ntstore2(lh2 + o2, (v2f){lhv[0], lhv[1]});
        ntstore2(hl2 + o2, (v2f){hlv[0], hlv[1]});
        ntstore2(hh2 + o2, (v2f){hhv[0], hhv[1]});
    }

    // ---- Level 3: 2x2 LL2 -> 1x1 per subband (32x32 planes) ----
    {
        const float a = ll2[0][0], b = ll2[0][1];
        const float c = ll2[1][0], d = ll2[1][1];
        const float s1 = a + b, s2 = c + d;
        const float d1 = a - b, d2 = c - d;
        const size_t o3 = (size_t)p * 1024
                        + (size_t)(8 * s + ty) * 32
                        + (size_t)tx;
        ntstore1(l3  + o3, 0.5f * (s1 + s2));
        ntstore1(lh3 + o3, 0.5f * (s1 - s2));
        ntstore1(hl3 + o3, 0.5f * (d1 + d2));
        ntstore1(hh3 + o3, 0.5f * (d1 - d2));
    }
}

extern "C" void kernel_launch(void* const* d_in, const int* in_sizes, int n_in,
                              void* d_out, int out_size, void* d_ws, size_t ws_size,
                              hipStream_t stream) {
    const float* x = (const float*)d_in[0];
    float* out = (float*)d_out;
    // 1024 planes * 4 strips = 4096 blocks, 256 threads each
    dwt3_haar<<<4096, 256, 0, stream>>>(x, out);
}